// Round 2
// baseline (850.053 us; speedup 1.0000x reference)
//
#include <hip/hip_runtime.h>
#include <math.h>

// Problem constants
#define BATCH 32
#define TLEN  4096
#define DDIM  512
#define BM    32      // rows per block (r8: halved -> 32 KB LDS, 3 blocks/CU)
#define BLOCK 512     // 8 waves; wave w owns output cols [64w, 64w+64)
// r8: TLP experiment. r6 (ILP structure A) and r7 (ILP structure B, half the
// per-wave instructions) measured IDENTICAL 385-400us with occupancy ~23%
// (= exactly 1 resident 8-wave block/CU). Theory: latency-bound with no
// independent waves to hide L2 stalls. This round: BM=32 (LDS 32 KB),
// no W prefetch regs, __launch_bounds__(512,6) caps VGPR<=85 -> 3 blocks/CU
// (24 waves, 6/SIMD). Latency hiding via TLP instead of ILP.
// Cost accepted: W re-read doubles to 4 GB L2 aggregate (~116us floor).

typedef __attribute__((ext_vector_type(8)))  short bf16x8;   // MFMA A/B frag
typedef __attribute__((ext_vector_type(16))) float f32x16;   // MFMA C/D frag (32x32)
typedef __attribute__((ext_vector_type(4)))  short s16x4;    // 8B LDS store

__device__ __forceinline__ short f32_to_bf16_rne(float f) {
    union { float f; unsigned int u; } v; v.f = f;
    unsigned int r = (v.u + 0x7FFFu + ((v.u >> 16) & 1u)) >> 16;
    return (short)r;
}
__device__ __forceinline__ float fast_tanh(float x) {
    x = fminf(fmaxf(x, -15.f), 15.f);
    float t = __expf(2.0f * x);
    return (t - 1.0f) / (t + 1.0f);
}

// XOR swizzle on 16B (8-short) granules. Measured 0 bank conflicts (r2-r6).
__device__ __forceinline__ int lds_idx(int r, int c) {
    int g = (c >> 3) ^ (r & 31);
    return r * DDIM + (g << 3) + (c & 7);
}

// --- kernel 1: W fp32 -> bf16, zero l/g accumulators -------------------------
__global__ void prep_kernel(const float* __restrict__ W1, const float* __restrict__ W2,
                            short* __restrict__ W1b, short* __restrict__ W2b,
                            float* __restrict__ lbuf, float* __restrict__ gbuf) {
    int i = blockIdx.x * blockDim.x + threadIdx.x;   // 0 .. 262143
    W1b[i] = f32_to_bf16_rne(W1[i]);
    W2b[i] = f32_to_bf16_rne(W2[i]);
    if (i < BATCH * DDIM) { lbuf[i] = 0.f; gbuf[i] = 0.f; }
}

// --- kernel 2: fused u=tanh(hW1^T+b1); s=uW2^T; accumulate l,g ---------------
__global__ __launch_bounds__(BLOCK, 6)   // 6 waves/EU = 3 blocks/CU, VGPR<=85
void main_kernel(const float* __restrict__ h,
                 const short* __restrict__ W1b,
                 const float* __restrict__ b1,
                 const short* __restrict__ W2b,
                 float* __restrict__ lbuf, float* __restrict__ gbuf) {
    __shared__ __align__(16) short sh[BM * DDIM];   // 32 KB: h tile, then u tile

    const int tid  = threadIdx.x;
    const int row0 = blockIdx.x * BM;
    const int b    = row0 / TLEN;       // BM divides TLEN: no batch straddle

    // ---- stage: global fp32 h -> LDS bf16 (coalesced float4 loads) ----
    {
        const float4* hp = (const float4*)(h + (size_t)row0 * DDIM);
        #pragma unroll
        for (int i = 0; i < (BM * DDIM / 4) / BLOCK; ++i) {   // 8 iters
            int idx  = tid + i * BLOCK;          // float4 index
            float4 v = hp[idx];
            int flat = idx * 4;
            int r = flat >> 9;                   // /512
            int c = flat & (DDIM - 1);
            s16x4 p;
            p.x = f32_to_bf16_rne(v.x); p.y = f32_to_bf16_rne(v.y);
            p.z = f32_to_bf16_rne(v.z); p.w = f32_to_bf16_rne(v.w);
            *(s16x4*)&sh[lds_idx(r, c)] = p;
        }
    }
    __syncthreads();

    const int wave = tid >> 6;
    const int lane = tid & 63;
    const int l32  = lane & 31;
    const int h5   = lane >> 5;       // 0/1
    const int e0   = wave * 64;       // this wave's 64-col slice (both GEMMs)

    // ========== GEMM1 (swapped): C[e][t] = sum_d W1[e][d] * h[t][d] ==========
    // A-frag = W1 rows (global/L2), B-frag = h^T from LDS. tb=1 (32 rows).
    f32x16 acc[2];                    // [eb]
    #pragma unroll
    for (int i = 0; i < 2; ++i)
        #pragma unroll
        for (int r = 0; r < 16; ++r) acc[i][r] = 0.f;

    const short* W1p = W1b + (size_t)(e0 + l32) * DDIM + 8 * h5;

    for (int k0 = 0; k0 < DDIM; k0 += 32) {
        bf16x8 hf[2];                 // [ksub]
        #pragma unroll
        for (int ks = 0; ks < 2; ++ks)
            hf[ks] = *(const bf16x8*)&sh[lds_idx(l32, k0 + ks * 16 + 8 * h5)];
        bf16x8 wf[2][2];              // [eb][ksub], loaded per-iter (TLP hides)
        #pragma unroll
        for (int eb = 0; eb < 2; ++eb)
            #pragma unroll
            for (int ks = 0; ks < 2; ++ks)
                wf[eb][ks] = *(const bf16x8*)(W1p + (size_t)eb * 32 * DDIM
                                              + k0 + ks * 16);
        #pragma unroll
        for (int eb = 0; eb < 2; ++eb)
            #pragma unroll
            for (int ks = 0; ks < 2; ++ks)
                acc[eb] = __builtin_amdgcn_mfma_f32_32x32x16_bf16(
                    wf[eb][ks], hf[ks], acc[eb], 0, 0, 0);
    }

    // bias + tanh. C/D map: col(t)=lane&31, row(e)=(r&3)+8*(r>>2)+4*h5 (+32*eb)
    #pragma unroll
    for (int eb = 0; eb < 2; ++eb) {
        float4 bv[4];
        #pragma unroll
        for (int q = 0; q < 4; ++q)
            bv[q] = *(const float4*)&b1[e0 + 32 * eb + 4 * h5 + 8 * q];
        #pragma unroll
        for (int r = 0; r < 16; ++r)
            acc[eb][r] = fast_tanh(acc[eb][r] + bv[r >> 2][r & 3]);
    }

    __syncthreads();   // all waves done reading h tile; safe to overwrite with u

    // write u^T frags as u[t][e]: lane owns fixed t=l32, 4-consecutive-e runs
    #pragma unroll
    for (int eb = 0; eb < 2; ++eb) {
        #pragma unroll
        for (int q = 0; q < 4; ++q) {
            int e = e0 + 32 * eb + 4 * h5 + 8 * q;
            s16x4 p;
            p.x = f32_to_bf16_rne(acc[eb][4 * q + 0]);
            p.y = f32_to_bf16_rne(acc[eb][4 * q + 1]);
            p.z = f32_to_bf16_rne(acc[eb][4 * q + 2]);
            p.w = f32_to_bf16_rne(acc[eb][4 * q + 3]);
            *(s16x4*)&sh[lds_idx(l32, e)] = p;
        }
    }
    __syncthreads();

    // ========== GEMM2 (normal): s[t][e2] = sum_e u[t][e] * W2[e2][e] =========
    f32x16 acc2[2];                   // [cb]
    #pragma unroll
    for (int i = 0; i < 2; ++i)
        #pragma unroll
        for (int r = 0; r < 16; ++r) acc2[i][r] = 0.f;

    const short* W2p = W2b + (size_t)(e0 + l32) * DDIM + 8 * h5;

    for (int k0 = 0; k0 < DDIM; k0 += 32) {
        bf16x8 uf[2];                 // [ksub]
        #pragma unroll
        for (int ks = 0; ks < 2; ++ks)
            uf[ks] = *(const bf16x8*)&sh[lds_idx(l32, k0 + ks * 16 + 8 * h5)];
        bf16x8 wf[2][2];              // [cb][ksub]
        #pragma unroll
        for (int cb = 0; cb < 2; ++cb)
            #pragma unroll
            for (int ks = 0; ks < 2; ++ks)
                wf[cb][ks] = *(const bf16x8*)(W2p + (size_t)cb * 32 * DDIM
                                              + k0 + ks * 16);
        #pragma unroll
        for (int cb = 0; cb < 2; ++cb)
            #pragma unroll
            for (int ks = 0; ks < 2; ++ks)
                acc2[cb] = __builtin_amdgcn_mfma_f32_32x32x16_bf16(
                    uf[ks], wf[cb][ks], acc2[cb], 0, 0, 0);
    }

    // epilogue: e = exp(s); l += e; g += e*h. t axis in-register:
    // lane holds 16 of 32 t's; partner (lane^32) holds the other 16.
    #pragma unroll
    for (int cb = 0; cb < 2; ++cb) {
        const int e2 = e0 + 32 * cb + l32;
        const float* hp2 = h + (size_t)row0 * DDIM + e2;
        float lsum = 0.f, gsum = 0.f;
        #pragma unroll
        for (int r = 0; r < 16; ++r) {
            int t = 4 * h5 + (r & 3) + 8 * (r >> 2);
            float ev = __expf(acc2[cb][r]);       // |s| small: no max-sub
            lsum += ev;
            gsum += ev * hp2[(size_t)t * DDIM];
        }
        lsum += __shfl_xor(lsum, 32);
        gsum += __shfl_xor(gsum, 32);
        if (h5 == 0) {
            atomicAdd(&lbuf[b * DDIM + e2], lsum);
            atomicAdd(&gbuf[b * DDIM + e2], gsum);
        }
    }
}

// --- kernel 3: out[d] = sum_b g[b,d] / l[b,d] --------------------------------
__global__ void finish_kernel(const float* __restrict__ lbuf,
                              const float* __restrict__ gbuf,
                              float* __restrict__ out) {
    int d = blockIdx.x * blockDim.x + threadIdx.x;   // 0..511
    float s = 0.f;
    #pragma unroll
    for (int b = 0; b < BATCH; ++b)
        s += gbuf[b * DDIM + d] / lbuf[b * DDIM + d];
    out[d] = s;
}

extern "C" void kernel_launch(void* const* d_in, const int* in_sizes, int n_in,
                              void* d_out, int out_size, void* d_ws, size_t ws_size,
                              hipStream_t stream) {
    const float* h  = (const float*)d_in[0];
    const float* W1 = (const float*)d_in[1];
    const float* b1 = (const float*)d_in[2];
    const float* W2 = (const float*)d_in[3];
    float* out = (float*)d_out;

    char* ws = (char*)d_ws;
    short* W1b = (short*)ws;                              // 512 KB
    short* W2b = (short*)(ws + 512 * 1024);               // 512 KB
    float* lbuf = (float*)(ws + 1024 * 1024);             // 64 KB
    float* gbuf = (float*)(ws + 1024 * 1024 + 64 * 1024); // 64 KB

    prep_kernel<<<(DDIM * DDIM) / 256, 256, 0, stream>>>(W1, W2, W1b, W2b, lbuf, gbuf);
    main_kernel<<<(BATCH * TLEN) / BM, BLOCK, 0, stream>>>(h, W1b, b1, W2b, lbuf, gbuf);
    finish_kernel<<<2, 256, 0, stream>>>(lbuf, gbuf, out);
}

// Round 3
// 537.180 us; speedup vs baseline: 1.5824x; 1.5824x over previous
//
#include <hip/hip_runtime.h>
#include <math.h>

// Problem constants
#define BATCH 32
#define TLEN  4096
#define DDIM  512
#define BM    64      // rows per block
#define BLOCK 512     // 8 waves; wave w owns output cols [64w, 64w+64) in ONE pass
// r9: W loads were the bottleneck. r6/r7/r8 all ~400+us with every pipe idle;
// per-block budget shows ~3750 cyc per k-iter vs ~250 cyc of issued work.
// Culprit: W fragment loads at 1KB lane stride ((e0+l32)*DDIM) -> each
// global_load_dwordx4 fans out to ~32 L2 transactions (~1-3k cyc to retire).
// Fix: prep_kernel pre-packs W1/W2 into MFMA-fragment-linear order
//   packed[((E*32 + C)*64 + lane)*8 + j]  (E = e>>5 row-tile, C = d>>4 k-chunk)
// so every k-loop W load is base + lane*16B: one coalesced 1KB L2 transaction.
// Geometry = r7 (BM=64, bounds(512,2), no spills, acc[2][2], 1-deep prefetch).

typedef __attribute__((ext_vector_type(8)))  short bf16x8;   // MFMA A/B frag
typedef __attribute__((ext_vector_type(16))) float f32x16;   // MFMA C/D frag (32x32)
typedef __attribute__((ext_vector_type(4)))  short s16x4;    // 8B LDS store

__device__ __forceinline__ short f32_to_bf16_rne(float f) {
    union { float f; unsigned int u; } v; v.f = f;
    unsigned int r = (v.u + 0x7FFFu + ((v.u >> 16) & 1u)) >> 16;
    return (short)r;
}
__device__ __forceinline__ float fast_tanh(float x) {
    x = fminf(fmaxf(x, -15.f), 15.f);
    float t = __expf(2.0f * x);
    return (t - 1.0f) / (t + 1.0f);
}

// XOR swizzle on 16B (8-short) granules. Measured 0 bank conflicts (r2-r6).
__device__ __forceinline__ int lds_idx(int r, int c) {
    int g = (c >> 3) ^ (r & 31);
    return r * DDIM + (g << 3) + (c & 7);
}

// --- kernel 1: W fp32 -> bf16 packed into MFMA-fragment order; zero l/g ------
// Thread i handles one 8-element j-run of both W1 and W2.
// Element (e, d): E=e>>5, r=e&31, C=d>>4, half=(d>>3)&1, j=d&7
//   packed[ ((E*32 + C)*64 + half*32 + r)*8 + j ]
// Kernel-side inverse (lane l = half*32 + r): tile (E,C), addr = tile*512+l*8
//   -> supplies W[E*32 + (l&31)][C*16 + 8*(l>>5) + j]  == old load expression.
__global__ void prep_kernel(const float* __restrict__ W1, const float* __restrict__ W2,
                            short* __restrict__ W1pk, short* __restrict__ W2pk,
                            float* __restrict__ lbuf, float* __restrict__ gbuf) {
    int i = blockIdx.x * blockDim.x + threadIdx.x;   // 0 .. 32767
    int e  = i >> 6;                 // source row
    int d0 = (i & 63) << 3;          // source col of this 8-run
    int E = e >> 5, r = e & 31, C = d0 >> 4, half = (d0 >> 3) & 1;
    size_t src = (size_t)e * DDIM + d0;
    size_t dst = ((size_t)(E * 32 + C) * 64 + half * 32 + r) * 8;
    bf16x8 p1, p2;
    #pragma unroll
    for (int j = 0; j < 8; ++j) {
        p1[j] = f32_to_bf16_rne(W1[src + j]);
        p2[j] = f32_to_bf16_rne(W2[src + j]);
    }
    *(bf16x8*)&W1pk[dst] = p1;
    *(bf16x8*)&W2pk[dst] = p2;
    if (i < BATCH * DDIM) { lbuf[i] = 0.f; gbuf[i] = 0.f; }
}

// --- kernel 2: fused u=tanh(hW1^T+b1); s=uW2^T; accumulate l,g ---------------
__global__ __launch_bounds__(BLOCK, 2)
void main_kernel(const float* __restrict__ h,
                 const short* __restrict__ W1pk,
                 const float* __restrict__ b1,
                 const short* __restrict__ W2pk,
                 float* __restrict__ lbuf, float* __restrict__ gbuf) {
    __shared__ __align__(16) short sh[BM * DDIM];   // 64 KB: h tile, then u tile

    const int tid  = threadIdx.x;
    const int row0 = blockIdx.x * BM;
    const int b    = row0 / TLEN;       // BM divides TLEN: no batch straddle

    // ---- stage: global fp32 h -> LDS bf16 (coalesced float4 loads) ----
    {
        const float4* hp = (const float4*)(h + (size_t)row0 * DDIM);
        #pragma unroll
        for (int i = 0; i < (BM * DDIM / 4) / BLOCK; ++i) {   // 16 iters
            int idx  = tid + i * BLOCK;          // float4 index
            float4 v = hp[idx];
            int flat = idx * 4;
            int r = flat >> 9;                   // /512
            int c = flat & (DDIM - 1);
            s16x4 p;
            p.x = f32_to_bf16_rne(v.x); p.y = f32_to_bf16_rne(v.y);
            p.z = f32_to_bf16_rne(v.z); p.w = f32_to_bf16_rne(v.w);
            *(s16x4*)&sh[lds_idx(r, c)] = p;
        }
    }
    __syncthreads();

    const int wave = tid >> 6;
    const int lane = tid & 63;
    const int l32  = lane & 31;
    const int h5   = lane >> 5;       // 0/1
    const int e0   = wave * 64;       // this wave's 64-col slice (both GEMMs)

    // ========== GEMM1 (swapped): C[e][t] = sum_d W1[e][d] * h[t][d] ==========
    // A-frag = W1 packed (coalesced: lane*16B), B-frag = h^T from LDS.
    f32x16 acc[2][2];                 // [eb][tb]
    #pragma unroll
    for (int i = 0; i < 2; ++i)
        #pragma unroll
        for (int j = 0; j < 2; ++j)
            #pragma unroll
            for (int r = 0; r < 16; ++r) acc[i][j][r] = 0.f;

    // per-wave fragment base: e-tile (e0>>5), lane's 8-elem slot
    const short* W1p = W1pk + (size_t)(e0 >> 5) * (32 * 512) + lane * 8;
    bf16x8 wc[2][2], wn[2][2];        // [eb][ksub], 1-iter prefetch
    #pragma unroll
    for (int eb = 0; eb < 2; ++eb)
        #pragma unroll
        for (int ks = 0; ks < 2; ++ks)
            wc[eb][ks] = *(const bf16x8*)(W1p + (eb * 32 + ks) * 512);

    for (int k0 = 0; k0 < DDIM; k0 += 32) {
        const int kb = k0 >> 4;
        bf16x8 hf[2][2];              // [tb][ksub]
        #pragma unroll
        for (int tb = 0; tb < 2; ++tb)
            #pragma unroll
            for (int ks = 0; ks < 2; ++ks)
                hf[tb][ks] = *(const bf16x8*)&sh[lds_idx(tb * 32 + l32,
                                                         k0 + ks * 16 + 8 * h5)];
        // prefetch next k-chunk (last iter overreads into adjacent ws: ok)
        #pragma unroll
        for (int eb = 0; eb < 2; ++eb)
            #pragma unroll
            for (int ks = 0; ks < 2; ++ks)
                wn[eb][ks] = *(const bf16x8*)(W1p + (eb * 32 + kb + 2 + ks) * 512);
        #pragma unroll
        for (int eb = 0; eb < 2; ++eb)
            #pragma unroll
            for (int tb = 0; tb < 2; ++tb)
                #pragma unroll
                for (int ks = 0; ks < 2; ++ks)
                    acc[eb][tb] = __builtin_amdgcn_mfma_f32_32x32x16_bf16(
                        wc[eb][ks], hf[tb][ks], acc[eb][tb], 0, 0, 0);
        #pragma unroll
        for (int eb = 0; eb < 2; ++eb)
            #pragma unroll
            for (int ks = 0; ks < 2; ++ks) wc[eb][ks] = wn[eb][ks];
    }

    // issue GEMM2's first W2 frags now: L2 latency hides under tanh+write+bars
    const short* W2p = W2pk + (size_t)(e0 >> 5) * (32 * 512) + lane * 8;
    bf16x8 w2c[2][2], w2n[2][2];      // [cb][ksub]
    #pragma unroll
    for (int cb = 0; cb < 2; ++cb)
        #pragma unroll
        for (int ks = 0; ks < 2; ++ks)
            w2c[cb][ks] = *(const bf16x8*)(W2p + (cb * 32 + ks) * 512);

    // bias + tanh. C/D map: col(t)=lane&31, row(e)=(r&3)+8*(r>>2)+4*h5 (+32*eb)
    #pragma unroll
    for (int eb = 0; eb < 2; ++eb) {
        float4 bv[4];
        #pragma unroll
        for (int q = 0; q < 4; ++q)
            bv[q] = *(const float4*)&b1[e0 + 32 * eb + 4 * h5 + 8 * q];
        #pragma unroll
        for (int tb = 0; tb < 2; ++tb)
            #pragma unroll
            for (int r = 0; r < 16; ++r)
                acc[eb][tb][r] = fast_tanh(acc[eb][tb][r] + bv[r >> 2][r & 3]);
    }

    __syncthreads();   // all waves done reading h tile; safe to overwrite with u

    // write u^T frags as u[t][e]: lane owns fixed t, 4-consecutive-e runs -> b64
    #pragma unroll
    for (int eb = 0; eb < 2; ++eb)
        #pragma unroll
        for (int tb = 0; tb < 2; ++tb) {
            int t = tb * 32 + l32;
            #pragma unroll
            for (int q = 0; q < 4; ++q) {
                int e = e0 + 32 * eb + 4 * h5 + 8 * q;
                s16x4 p;
                p.x = f32_to_bf16_rne(acc[eb][tb][4 * q + 0]);
                p.y = f32_to_bf16_rne(acc[eb][tb][4 * q + 1]);
                p.z = f32_to_bf16_rne(acc[eb][tb][4 * q + 2]);
                p.w = f32_to_bf16_rne(acc[eb][tb][4 * q + 3]);
                *(s16x4*)&sh[lds_idx(t, e)] = p;
            }
        }
    __syncthreads();

    // ========== GEMM2 (normal): s[t][e2] = sum_e u[t][e] * W2[e2][e] =========
    f32x16 acc2[2][2];                // [tb][cb]
    #pragma unroll
    for (int i = 0; i < 2; ++i)
        #pragma unroll
        for (int j = 0; j < 2; ++j)
            #pragma unroll
            for (int r = 0; r < 16; ++r) acc2[i][j][r] = 0.f;

    for (int k0 = 0; k0 < DDIM; k0 += 32) {
        const int kb = k0 >> 4;
        bf16x8 uf[2][2];              // [tb][ksub]
        #pragma unroll
        for (int tb = 0; tb < 2; ++tb)
            #pragma unroll
            for (int ks = 0; ks < 2; ++ks)
                uf[tb][ks] = *(const bf16x8*)&sh[lds_idx(tb * 32 + l32,
                                                         k0 + ks * 16 + 8 * h5)];
        #pragma unroll
        for (int cb = 0; cb < 2; ++cb)
            #pragma unroll
            for (int ks = 0; ks < 2; ++ks)
                w2n[cb][ks] = *(const bf16x8*)(W2p + (cb * 32 + kb + 2 + ks) * 512);
        #pragma unroll
        for (int tb = 0; tb < 2; ++tb)
            #pragma unroll
            for (int cb = 0; cb < 2; ++cb)
                #pragma unroll
                for (int ks = 0; ks < 2; ++ks)
                    acc2[tb][cb] = __builtin_amdgcn_mfma_f32_32x32x16_bf16(
                        uf[tb][ks], w2c[cb][ks], acc2[tb][cb], 0, 0, 0);
        #pragma unroll
        for (int cb = 0; cb < 2; ++cb)
            #pragma unroll
            for (int ks = 0; ks < 2; ++ks) w2c[cb][ks] = w2n[cb][ks];
    }

    // epilogue: e = exp(s); l += e; g += e*h. t axis is in-register:
    // per cb, lane holds 32 of 64 t's; partner (lane^32) holds the other 32.
    #pragma unroll
    for (int cb = 0; cb < 2; ++cb) {
        const int e2 = e0 + 32 * cb + l32;
        const float* hp2 = h + (size_t)row0 * DDIM + e2;
        float lsum = 0.f, gsum = 0.f;
        #pragma unroll
        for (int tb = 0; tb < 2; ++tb)
            #pragma unroll
            for (int r = 0; r < 16; ++r) {
                int t = tb * 32 + 4 * h5 + (r & 3) + 8 * (r >> 2);
                float ev = __expf(acc2[tb][cb][r]);   // |s| small: no max-sub
                lsum += ev;
                gsum += ev * hp2[(size_t)t * DDIM];
            }
        lsum += __shfl_xor(lsum, 32);
        gsum += __shfl_xor(gsum, 32);
        if (h5 == 0) {
            atomicAdd(&lbuf[b * DDIM + e2], lsum);
            atomicAdd(&gbuf[b * DDIM + e2], gsum);
        }
    }
}

// --- kernel 3: out[d] = sum_b g[b,d] / l[b,d] --------------------------------
__global__ void finish_kernel(const float* __restrict__ lbuf,
                              const float* __restrict__ gbuf,
                              float* __restrict__ out) {
    int d = blockIdx.x * blockDim.x + threadIdx.x;   // 0..511
    float s = 0.f;
    #pragma unroll
    for (int b = 0; b < BATCH; ++b)
        s += gbuf[b * DDIM + d] / lbuf[b * DDIM + d];
    out[d] = s;
}

extern "C" void kernel_launch(void* const* d_in, const int* in_sizes, int n_in,
                              void* d_out, int out_size, void* d_ws, size_t ws_size,
                              hipStream_t stream) {
    const float* h  = (const float*)d_in[0];
    const float* W1 = (const float*)d_in[1];
    const float* b1 = (const float*)d_in[2];
    const float* W2 = (const float*)d_in[3];
    float* out = (float*)d_out;

    char* ws = (char*)d_ws;
    short* W1pk = (short*)ws;                             // 512 KB (packed)
    short* W2pk = (short*)(ws + 512 * 1024);              // 512 KB (packed)
    float* lbuf = (float*)(ws + 1024 * 1024);             // 64 KB
    float* gbuf = (float*)(ws + 1024 * 1024 + 64 * 1024); // 64 KB

    prep_kernel<<<128, 256, 0, stream>>>(W1, W2, W1pk, W2pk, lbuf, gbuf);
    main_kernel<<<(BATCH * TLEN) / BM, BLOCK, 0, stream>>>(h, W1pk, b1, W2pk, lbuf, gbuf);
    finish_kernel<<<2, 256, 0, stream>>>(lbuf, gbuf, out);
}